// Round 10
// baseline (438.127 us; speedup 1.0000x reference)
//
#include <hip/hip_runtime.h>

// CausalAffineAutoregFlow — MI355X bf16-MFMA implementation, round 10.
//
// R10 = R9 structure (32x32x16, 32 rows/wave, self-contained wave) with a
// register-pressure redesign to kill accvgpr churn (~1100 VALU insts/step):
//  - A2 (224 regs) pinned AGPR (only weights in regs).
//  - A1 (16 frags) and A3 (14 frags) in LDS, read per use (30 ds_read_b128
//    per step, issue-cheap, latency hidden under MFMA chains).
//  - Fused dual-MLP: s/t interleaved (2-way ILP); per-T and per-M packs so
//    each f32x16 tile dies immediately after packing. Peak live activations
//    ~144 VGPRs; total VGPR ~230 <= 256 -> accumulators stay VGPR-resident.
//
// Layout conventions (R8-identical):
//  - C/D: col=lane&31, row=(reg&3)+8*(reg>>2)+4*(lane>>5)
//  - layer-1 B k-slot sigma = 16c+8h+j (dims); layer-2/3 chunk kk covers
//    neuron n = 32*(kk>>1) + (q&3) + 8*(q>>2) + 4h, q=(kk&1)*8+j.
//  - bias folds: b1 at dim-31 slot (C[31][i]==0 always); b2/b3 at padded
//    neuron n==100 slot = chunk 6, h==1, j==0 (pack injects 1.0 there).

typedef __attribute__((ext_vector_type(8))) short short8;
typedef __attribute__((ext_vector_type(4))) float f32x4;
typedef __attribute__((ext_vector_type(16))) float f32x16;
typedef __attribute__((ext_vector_type(4))) unsigned int uint4v;

#define WPK_U16 44032        // 2 MLPs x 43 frags x 512 u16
#define MPK_OFF_BYTES 88064  // 44032*2, 16B aligned
#define NBLK 1024
#define REPS 4

__device__ __forceinline__ unsigned int bf16u(float v) {
  unsigned int b = __float_as_uint(v);
  b += 0x7FFFu + ((b >> 16) & 1u);   // RNE round to bf16
  return b >> 16;
}

__device__ __forceinline__ unsigned int cvtpk(float lo, float hi) {
  unsigned int r;
  asm("v_cvt_pk_bf16_f32 %0, %1, %2" : "=v"(r) : "v"(lo), "v"(hi));
  return r;
}

// Packed relu on 2xbf16 (R7/R8-proven).
__device__ __forceinline__ unsigned int pkrelu(unsigned int x) {
  unsigned int r;
  asm("v_pk_max_i16 %0, %1, %2" : "=v"(r) : "v"(x), "v"(0u));
  return r;
}

// Pack C/D regs c*8..c*8+7 of one 32-tile into a B fragment (relu'd).
__device__ __forceinline__ short8 packBC(const f32x16 &ht, int c) {
  uint4v u;
  u.x = pkrelu(cvtpk(ht[c * 8 + 0], ht[c * 8 + 1]));
  u.y = pkrelu(cvtpk(ht[c * 8 + 2], ht[c * 8 + 3]));
  u.z = pkrelu(cvtpk(ht[c * 8 + 4], ht[c * 8 + 5]));
  u.w = pkrelu(cvtpk(ht[c * 8 + 6], ht[c * 8 + 7]));
  return __builtin_bit_cast(short8, u);
}

// Chunk 6 (tile 3, c=0) with bias slot: (h==1, j==0) := 1.0 (neuron 100).
__device__ __forceinline__ short8 packBC6(const f32x16 &ht, bool bh) {
  uint4v u;
  float lo = bh ? 1.0f : ht[0];
  u.x = pkrelu(cvtpk(lo, ht[1]));
  u.y = pkrelu(cvtpk(ht[2], ht[3]));
  u.z = pkrelu(cvtpk(ht[4], ht[5]));
  u.w = pkrelu(cvtpk(ht[6], ht[7]));
  return __builtin_bit_cast(short8, u);
}

// Fused dual-MLP, 32 batch cols. a1p/a3p = LDS base + lane (frag f at
// p[f*64]). a2 = AGPR-pinned register fragments. Outputs pre-sigmoid
// scalars, valid on all lanes (W3 row-replicated in prepack).
__device__ __forceinline__ void mlp2_32(
    const short8 (&a2s)[4][7], const short8 (&a2t)[4][7],
    const short8 *__restrict__ a1p, const short8 *__restrict__ a3p,
    short8 x0, short8 x1, bool bh, float &sp, float &tp) {
  const f32x16 zz = {0.f, 0.f, 0.f, 0.f, 0.f, 0.f, 0.f, 0.f,
                     0.f, 0.f, 0.f, 0.f, 0.f, 0.f, 0.f, 0.f};
  short8 bfs[7], bft[7];
#pragma unroll
  for (int T = 0; T < 4; ++T) {
    f32x16 hs = __builtin_amdgcn_mfma_f32_32x32x16_bf16(a1p[(T * 2) * 64], x0, zz, 0, 0, 0);
    f32x16 ht = __builtin_amdgcn_mfma_f32_32x32x16_bf16(a1p[(8 + T * 2) * 64], x0, zz, 0, 0, 0);
    hs = __builtin_amdgcn_mfma_f32_32x32x16_bf16(a1p[(T * 2 + 1) * 64], x1, hs, 0, 0, 0);
    ht = __builtin_amdgcn_mfma_f32_32x32x16_bf16(a1p[(8 + T * 2 + 1) * 64], x1, ht, 0, 0, 0);
    if (T < 3) {
      bfs[2 * T] = packBC(hs, 0); bfs[2 * T + 1] = packBC(hs, 1);
      bft[2 * T] = packBC(ht, 0); bft[2 * T + 1] = packBC(ht, 1);
    } else {
      bfs[6] = packBC6(hs, bh);
      bft[6] = packBC6(ht, bh);
    }
  }
  short8 bgs[7], bgt[7];
#pragma unroll
  for (int M = 0; M < 4; ++M) {
    f32x16 hs = __builtin_amdgcn_mfma_f32_32x32x16_bf16(a2s[M][0], bfs[0], zz, 0, 0, 0);
    f32x16 ht = __builtin_amdgcn_mfma_f32_32x32x16_bf16(a2t[M][0], bft[0], zz, 0, 0, 0);
#pragma unroll
    for (int kk = 1; kk < 7; ++kk) {
      hs = __builtin_amdgcn_mfma_f32_32x32x16_bf16(a2s[M][kk], bfs[kk], hs, 0, 0, 0);
      ht = __builtin_amdgcn_mfma_f32_32x32x16_bf16(a2t[M][kk], bft[kk], ht, 0, 0, 0);
    }
    if (M < 3) {
      bgs[2 * M] = packBC(hs, 0); bgs[2 * M + 1] = packBC(hs, 1);
      bgt[2 * M] = packBC(ht, 0); bgt[2 * M + 1] = packBC(ht, 1);
    } else {
      bgs[6] = packBC6(hs, bh);
      bgt[6] = packBC6(ht, bh);
    }
  }
  f32x16 as0 = __builtin_amdgcn_mfma_f32_32x32x16_bf16(a3p[0 * 64], bgs[0], zz, 0, 0, 0);
  f32x16 at0 = __builtin_amdgcn_mfma_f32_32x32x16_bf16(a3p[7 * 64], bgt[0], zz, 0, 0, 0);
  f32x16 as1 = __builtin_amdgcn_mfma_f32_32x32x16_bf16(a3p[1 * 64], bgs[1], zz, 0, 0, 0);
  f32x16 at1 = __builtin_amdgcn_mfma_f32_32x32x16_bf16(a3p[8 * 64], bgt[1], zz, 0, 0, 0);
  as0 = __builtin_amdgcn_mfma_f32_32x32x16_bf16(a3p[2 * 64], bgs[2], as0, 0, 0, 0);
  at0 = __builtin_amdgcn_mfma_f32_32x32x16_bf16(a3p[9 * 64], bgt[2], at0, 0, 0, 0);
  as1 = __builtin_amdgcn_mfma_f32_32x32x16_bf16(a3p[3 * 64], bgs[3], as1, 0, 0, 0);
  at1 = __builtin_amdgcn_mfma_f32_32x32x16_bf16(a3p[10 * 64], bgt[3], at1, 0, 0, 0);
  as0 = __builtin_amdgcn_mfma_f32_32x32x16_bf16(a3p[4 * 64], bgs[4], as0, 0, 0, 0);
  at0 = __builtin_amdgcn_mfma_f32_32x32x16_bf16(a3p[11 * 64], bgt[4], at0, 0, 0, 0);
  as1 = __builtin_amdgcn_mfma_f32_32x32x16_bf16(a3p[5 * 64], bgs[5], as1, 0, 0, 0);
  at1 = __builtin_amdgcn_mfma_f32_32x32x16_bf16(a3p[12 * 64], bgt[5], at1, 0, 0, 0);
  as0 = __builtin_amdgcn_mfma_f32_32x32x16_bf16(a3p[6 * 64], bgs[6], as0, 0, 0, 0);
  at0 = __builtin_amdgcn_mfma_f32_32x32x16_bf16(a3p[13 * 64], bgt[6], at0, 0, 0, 0);
  sp = as0[0] + as1[0];
  tp = at0[0] + at1[0];
}

// ---------------- prepack: fp32 weights -> packed bf16 A-fragments ----------
// Frags per MLP (43): A1 f=2T+c (8); A2 f=8+7M+kk (28); A3 f=36+kk (7).
__global__ void prepack_kernel(const float *__restrict__ C,
                               const float *__restrict__ sW1, const float *__restrict__ sb1,
                               const float *__restrict__ sW2, const float *__restrict__ sb2,
                               const float *__restrict__ sW3, const float *__restrict__ sb3,
                               const float *__restrict__ tW1, const float *__restrict__ tb1,
                               const float *__restrict__ tW2, const float *__restrict__ tb2,
                               const float *__restrict__ tW3, const float *__restrict__ tb3,
                               unsigned short *__restrict__ wpk,
                               unsigned int *__restrict__ mpk) {
  int gid = blockIdx.x * 256 + threadIdx.x;
  if (gid < WPK_U16) {
    int which = gid / 22016;
    int a = gid % 22016;
    const float *W1 = which ? tW1 : sW1;
    const float *B1 = which ? tb1 : sb1;
    const float *W2 = which ? tW2 : sW2;
    const float *B2 = which ? tb2 : sb2;
    const float *W3 = which ? tW3 : sW3;
    const float *B3 = which ? tb3 : sb3;
    int f = a >> 9;
    int l = (a >> 3) & 63;
    int j = a & 7;
    int hh = l >> 5, cl = l & 31;
    float v = 0.f;
    if (f < 8) {                       // A1
      int T = f >> 1, c = f & 1;
      int m = 32 * T + cl;
      int d = 16 * c + 8 * hh + j;
      if (m < 100) v = (d == 31) ? B1[m] : W1[d * 100 + m];
    } else if (f < 36) {               // A2
      int ff = f - 8;
      int M = ff / 7, kk = ff % 7;
      int m = 32 * M + cl;
      int q = (kk & 1) * 8 + j;
      int n = 32 * (kk >> 1) + (q & 3) + 8 * (q >> 2) + 4 * hh;
      if (m < 100) {
        if (n < 100) v = W2[n * 100 + m];
        else if (n == 100) v = B2[m];
      }
    } else {                           // A3, replicated across rows
      int kk = f - 36;
      int q = (kk & 1) * 8 + j;
      int n = 32 * (kk >> 1) + (q & 3) + 8 * (q >> 2) + 4 * hh;
      if (n < 100) v = W3[n];
      else if (n == 100) v = B3[0];
    }
    wpk[gid] = (unsigned short)bf16u(v);
  } else if (gid < WPK_U16 + 512) {    // masks: [i][h][p]
    int idx = gid - WPK_U16;
    int i = idx >> 4;
    int hh = (idx >> 3) & 1;
    int p = idx & 7;
    int d0 = 16 * (p >> 2) + 8 * hh + 2 * (p & 3);
    unsigned int u = 0;
    if (C[d0 * 32 + i] != 0.f) u |= 0x0000FFFFu;
    if (C[(d0 + 1) * 32 + i] != 0.f) u |= 0xFFFF0000u;
    mpk[idx] = u;
  }
}

// ---------------- main kernel: one wave, 32 batch rows per tile -------------
__global__ __launch_bounds__(64, 1) void flow_main(
    const float *__restrict__ e, const unsigned short *__restrict__ wpk,
    const unsigned int *__restrict__ mpk, float *__restrict__ out) {
  const int lane = threadIdx.x;
  const int h = lane >> 5;
  const int col = lane & 31;
  const bool hb = (h == 1);

  __shared__ __align__(16) unsigned int msk[512];
  __shared__ short8 a1l[1024];  // 2 MLPs x 8 frags x 64 lanes = 16 KB
  __shared__ short8 a3l[896];   // 2 MLPs x 7 frags x 64 lanes = 14 KB
  {
    const uint4v *s = (const uint4v *)mpk;
    uint4v *d = (uint4v *)msk;
    d[lane] = s[lane];
    d[lane + 64] = s[lane + 64];
  }
  const short8 *wfr = (const short8 *)wpk;
#pragma unroll
  for (int f = 0; f < 16; ++f) {
    int mlp = f >> 3, fc = f & 7;
    a1l[f * 64 + lane] = wfr[(mlp * 43 + fc) * 64 + lane];
  }
#pragma unroll
  for (int f = 0; f < 14; ++f) {
    int mlp = f / 7, kk = f % 7;
    a3l[f * 64 + lane] = wfr[(mlp * 43 + 36 + kk) * 64 + lane];
  }

  short8 a2s[4][7], a2t[4][7];
#pragma unroll
  for (int M = 0; M < 4; ++M)
#pragma unroll
    for (int k = 0; k < 7; ++k) {
      a2s[M][k] = wfr[(8 + M * 7 + k) * 64 + lane];
      a2t[M][k] = wfr[(43 + 8 + M * 7 + k) * 64 + lane];
    }
  // Pin A2 (224 regs) to AGPRs; everything else stays VGPR.
#pragma unroll
  for (int M = 0; M < 4; ++M)
#pragma unroll
    for (int k = 0; k < 7; ++k) {
      asm volatile("" : "+a"(a2s[M][k]));
      asm volatile("" : "+a"(a2t[M][k]));
    }
  __syncthreads();

  const short8 *a1p = a1l + lane;
  const short8 *a3p = a3l + lane;

#pragma unroll 1
  for (int rep = 0; rep < REPS; ++rep) {
    const long row = ((long)blockIdx.x * REPS + rep) * 32 + col;
    const float *ep = e + row * 32;
    f32x4 eA = *(const f32x4 *)(ep + 8 * h);
    f32x4 eB = *(const f32x4 *)(ep + 8 * h + 4);
    f32x4 eC = *(const f32x4 *)(ep + 16 + 8 * h);
    f32x4 eD = *(const f32x4 *)(ep + 16 + 8 * h + 4);
    unsigned int zr[8] = {0u, 0u, 0u, 0u, 0u, 0u, 0u, 0u};
    float ld = 0.f;
    uint4v ma = *(const uint4v *)&msk[h * 8];
    uint4v mb = *(const uint4v *)&msk[h * 8 + 4];

#pragma unroll 1
    for (int i8 = 0; i8 < 4; ++i8) {
      const bool tg = (h == (i8 & 1));
#pragma unroll
      for (int u = 0; u < 8; ++u) {
        const int nx = (((i8 * 8 + u) + 1) & 31) * 16 + h * 8;
        uint4v man = *(const uint4v *)&msk[nx];
        uint4v mbn = *(const uint4v *)&msk[nx + 4];

        uint4v xu0, xu1;
        xu0.x = zr[0] & ma.x; xu0.y = zr[1] & ma.y;
        xu0.z = zr[2] & ma.z; xu0.w = zr[3] & ma.w;
        xu1.x = zr[4] & mb.x; xu1.y = zr[5] & mb.y;
        xu1.z = zr[6] & mb.z; xu1.w = zr[7] & mb.w;
        if (hb) xu1.w = (xu1.w & 0x0000FFFFu) | 0x3F800000u;  // dim31 := 1.0
        short8 x0 = __builtin_bit_cast(short8, xu0);
        short8 x1 = __builtin_bit_cast(short8, xu1);

        float sp, tp;
        mlp2_32(a2s, a2t, a1p, a3p, x0, x1, hb, sp, tp);
        float sv = __fdividef(1.f, 1.f + __expf(-sp));
        float tv = __fdividef(1.f, 1.f + __expf(-tp));
        ld += sv;

        float es0 = (u < 4) ? eA[u] : eB[u - 4];
        float es1 = (u < 4) ? eC[u] : eD[u - 4];
        float es = (i8 < 2) ? es0 : es1;
        float zn = __expf(sv) * es + tv;
        unsigned int r = cvtpk(zn, zn);
        const int p = u >> 1;
        const bool hi = (u & 1) != 0;
        if (i8 < 2) {
          unsigned int mrg = hi ? ((zr[p] & 0x0000FFFFu) | (r & 0xFFFF0000u))
                                : ((zr[p] & 0xFFFF0000u) | (r & 0x0000FFFFu));
          zr[p] = tg ? mrg : zr[p];
        } else {
          unsigned int mrg = hi ? ((zr[4 + p] & 0x0000FFFFu) | (r & 0xFFFF0000u))
                                : ((zr[4 + p] & 0xFFFF0000u) | (r & 0x0000FFFFu));
          zr[4 + p] = tg ? mrg : zr[4 + p];
        }
        ma = man;
        mb = mbn;
      }
    }

    float *zo = out + row * 32;
    f32x4 o;
    o[0] = __uint_as_float(zr[0] << 16);
    o[1] = __uint_as_float(zr[0] & 0xFFFF0000u);
    o[2] = __uint_as_float(zr[1] << 16);
    o[3] = __uint_as_float(zr[1] & 0xFFFF0000u);
    *(f32x4 *)(zo + 8 * h) = o;
    o[0] = __uint_as_float(zr[2] << 16);
    o[1] = __uint_as_float(zr[2] & 0xFFFF0000u);
    o[2] = __uint_as_float(zr[3] << 16);
    o[3] = __uint_as_float(zr[3] & 0xFFFF0000u);
    *(f32x4 *)(zo + 8 * h + 4) = o;
    o[0] = __uint_as_float(zr[4] << 16);
    o[1] = __uint_as_float(zr[4] & 0xFFFF0000u);
    o[2] = __uint_as_float(zr[5] << 16);
    o[3] = __uint_as_float(zr[5] & 0xFFFF0000u);
    *(f32x4 *)(zo + 16 + 8 * h) = o;
    o[0] = __uint_as_float(zr[6] << 16);
    o[1] = __uint_as_float(zr[6] & 0xFFFF0000u);
    o[2] = __uint_as_float(zr[7] << 16);
    o[3] = __uint_as_float(zr[7] & 0xFFFF0000u);
    *(f32x4 *)(zo + 16 + 8 * h + 4) = o;
    if (h == 0) out[(long)131072 * 32 + row] = ld;
  }
}

extern "C" void kernel_launch(void *const *d_in, const int *in_sizes, int n_in,
                              void *d_out, int out_size, void *d_ws, size_t ws_size,
                              hipStream_t stream) {
  const float *e  = (const float *)d_in[0];
  const float *C  = (const float *)d_in[1];
  const float *sW1 = (const float *)d_in[2];
  const float *sb1 = (const float *)d_in[3];
  const float *sW2 = (const float *)d_in[4];
  const float *sb2 = (const float *)d_in[5];
  const float *sW3 = (const float *)d_in[6];
  const float *sb3 = (const float *)d_in[7];
  const float *tW1 = (const float *)d_in[8];
  const float *tb1 = (const float *)d_in[9];
  const float *tW2 = (const float *)d_in[10];
  const float *tb2 = (const float *)d_in[11];
  const float *tW3 = (const float *)d_in[12];
  const float *tb3 = (const float *)d_in[13];

  unsigned short *wpk = (unsigned short *)d_ws;
  unsigned int *mpk = (unsigned int *)((char *)d_ws + MPK_OFF_BYTES);
  float *out = (float *)d_out;

  prepack_kernel<<<dim3(174), dim3(256), 0, stream>>>(
      C, sW1, sb1, sW2, sb2, sW3, sb3, tW1, tb1, tW2, tb2, tW3, tb3, wpk, mpk);
  flow_main<<<dim3(NBLK), dim3(64), 0, stream>>>(e, wpk, mpk, out);
}

// Round 11
// 270.517 us; speedup vs baseline: 1.6196x; 1.6196x over previous
//
#include <hip/hip_runtime.h>

// CausalAffineAutoregFlow — MI355X bf16-MFMA implementation, round 11.
//
// R11 = R7 (passing, 292 us: 16x16x32, 16 rows/wave, fused dual-MLP,
// packed relu, parallel layer-3) + ONE change: A2 and A3 fragments of BOTH
// MLPs pinned to AGPRs (224 + 32 = 256, exact AGPR fit) via no-op asm "+a".
// A1 (56 regs) + working set (~175) stay in VGPRs (~231 <= 256).
// Target: the ~500 VALU insts/step of v_accvgpr_read/write churn measured
// in R7 (VALUBusy 53% vs ~290 needed insts). R10 proved weights must stay
// in the register file (LDS A-operands cost 1.5x at 1 wave/SIMD).
//
// Slot conventions (R2/R7-identical):
//  - B/x/z/e per-lane slots j=0..7: logical dim = 8*(lane>>4)+j
//  - H-derived B chunk c slot (G,j): logical neuron 32c+(j>>2)*16+4G+(j&3)
//  - bias folds: b1 at dim-31 slot (x[31]==0 always since C[31][i]==0);
//    b2/b3 at padded neuron k==100 slot (chunk 3, G==1, j==0 := 1.0)

typedef __attribute__((ext_vector_type(8))) short short8;
typedef __attribute__((ext_vector_type(4))) float f32x4;
typedef __attribute__((ext_vector_type(4))) unsigned int uint4v;

#define WPK_U16 39936
#define MPK_OFF_BYTES 79872  // 39936*2, 16B aligned
#define NBLK 2048
#define REPS 4

__device__ __forceinline__ unsigned int bf16u(float v) {
  unsigned int b = __float_as_uint(v);
  b += 0x7FFFu + ((b >> 16) & 1u);   // RNE round to bf16
  return b >> 16;
}

// One-instruction packed f32->bf16x2 (lo = src0, hi = src1), RNE.
__device__ __forceinline__ unsigned int cvtpk(float lo, float hi) {
  unsigned int r;
  asm("v_cvt_pk_bf16_f32 %0, %1, %2" : "=v"(r) : "v"(lo), "v"(hi));
  return r;
}

// Packed relu on 2xbf16: i16 max with 0 (R7-proven).
__device__ __forceinline__ unsigned int pkrelu(unsigned int x) {
  unsigned int r;
  asm("v_pk_max_i16 %0, %1, %2" : "=v"(r) : "v"(x), "v"(0u));
  return r;
}

// Pack 7 accumulator tiles -> 4 B-fragment chunks, relu in packed domain.
__device__ __forceinline__ void pack_h(const f32x4 (&h)[7], uint4v (&B)[4],
                                       bool g1) {
#pragma unroll
  for (int c = 0; c < 3; ++c) {
    B[c].x = pkrelu(cvtpk(h[2 * c][0], h[2 * c][1]));
    B[c].y = pkrelu(cvtpk(h[2 * c][2], h[2 * c][3]));
    B[c].z = pkrelu(cvtpk(h[2 * c + 1][0], h[2 * c + 1][1]));
    B[c].w = pkrelu(cvtpk(h[2 * c + 1][2], h[2 * c + 1][3]));
  }
  float v0 = g1 ? 1.0f : h[6][0];   // bias slot k==100 -> (G1,j0) := 1.0
  B[3].x = pkrelu(cvtpk(v0, h[6][1]));
  B[3].y = pkrelu(cvtpk(h[6][2], h[6][3]));
  B[3].z = 0u;
  B[3].w = 0u;
}

// Fused dual-MLP evaluation (R7): s and t chains interleaved. Outputs
// pre-sigmoid scalars (valid on all lanes; W3 row-replicated in prepack).
__device__ __forceinline__ void mlp2_eval(
    const short8 (&a1s)[7], const short8 (&a2s)[7][4], const short8 (&a3s)[4],
    const short8 (&a1t)[7], const short8 (&a2t)[7][4], const short8 (&a3t)[4],
    short8 x, bool g1, float &sp, float &tp) {
  const f32x4 zz = {0.f, 0.f, 0.f, 0.f};
  // ---- layer 1 (14 independent MFMAs) ----
  f32x4 h1s[7], h1t[7];
#pragma unroll
  for (int t = 0; t < 7; ++t) {
    h1s[t] = __builtin_amdgcn_mfma_f32_16x16x32_bf16(a1s[t], x, zz, 0, 0, 0);
    h1t[t] = __builtin_amdgcn_mfma_f32_16x16x32_bf16(a1t[t], x, zz, 0, 0, 0);
  }
  uint4v B1s[4], B1t[4];
  pack_h(h1s, B1s, g1);
  pack_h(h1t, B1t, g1);
  // ---- layer 2 (2 x 28 MFMAs, 14 independent chains) ----
  f32x4 h2s[7], h2t[7];
#pragma unroll
  for (int t = 0; t < 7; ++t) { h2s[t] = zz; h2t[t] = zz; }
#pragma unroll
  for (int c = 0; c < 4; ++c) {
    short8 Bs = __builtin_bit_cast(short8, B1s[c]);
    short8 Bt = __builtin_bit_cast(short8, B1t[c]);
#pragma unroll
    for (int t = 0; t < 7; ++t) {
      h2s[t] = __builtin_amdgcn_mfma_f32_16x16x32_bf16(a2s[t][c], Bs, h2s[t], 0, 0, 0);
      h2t[t] = __builtin_amdgcn_mfma_f32_16x16x32_bf16(a2t[t][c], Bt, h2t[t], 0, 0, 0);
    }
  }
  uint4v B2s[4], B2t[4];
  pack_h(h2s, B2s, g1);
  pack_h(h2t, B2t, g1);
  // ---- layer 3: 4 independent accs per MLP (no serial MFMA chain) ----
  f32x4 as0 = __builtin_amdgcn_mfma_f32_16x16x32_bf16(a3s[0], __builtin_bit_cast(short8, B2s[0]), zz, 0, 0, 0);
  f32x4 at0 = __builtin_amdgcn_mfma_f32_16x16x32_bf16(a3t[0], __builtin_bit_cast(short8, B2t[0]), zz, 0, 0, 0);
  f32x4 as1 = __builtin_amdgcn_mfma_f32_16x16x32_bf16(a3s[1], __builtin_bit_cast(short8, B2s[1]), zz, 0, 0, 0);
  f32x4 at1 = __builtin_amdgcn_mfma_f32_16x16x32_bf16(a3t[1], __builtin_bit_cast(short8, B2t[1]), zz, 0, 0, 0);
  f32x4 as2 = __builtin_amdgcn_mfma_f32_16x16x32_bf16(a3s[2], __builtin_bit_cast(short8, B2s[2]), zz, 0, 0, 0);
  f32x4 at2 = __builtin_amdgcn_mfma_f32_16x16x32_bf16(a3t[2], __builtin_bit_cast(short8, B2t[2]), zz, 0, 0, 0);
  f32x4 as3 = __builtin_amdgcn_mfma_f32_16x16x32_bf16(a3s[3], __builtin_bit_cast(short8, B2s[3]), zz, 0, 0, 0);
  f32x4 at3 = __builtin_amdgcn_mfma_f32_16x16x32_bf16(a3t[3], __builtin_bit_cast(short8, B2t[3]), zz, 0, 0, 0);
  sp = (as0[0] + as1[0]) + (as2[0] + as3[0]);
  tp = (at0[0] + at1[0]) + (at2[0] + at3[0]);
}

// ---------------- prepack: fp32 weights -> packed bf16 A-fragments ----------
__global__ void prepack_kernel(const float *__restrict__ C,
                               const float *__restrict__ sW1, const float *__restrict__ sb1,
                               const float *__restrict__ sW2, const float *__restrict__ sb2,
                               const float *__restrict__ sW3, const float *__restrict__ sb3,
                               const float *__restrict__ tW1, const float *__restrict__ tb1,
                               const float *__restrict__ tW2, const float *__restrict__ tb2,
                               const float *__restrict__ tW3, const float *__restrict__ tb3,
                               unsigned short *__restrict__ wpk,
                               unsigned int *__restrict__ mpk) {
  int gid = blockIdx.x * 256 + threadIdx.x;
  if (gid < WPK_U16) {
    int which = gid / 19968;
    int a = gid % 19968;
    const float *W1 = which ? tW1 : sW1;
    const float *B1 = which ? tb1 : sb1;
    const float *W2 = which ? tW2 : sW2;
    const float *B2 = which ? tb2 : sb2;
    const float *W3 = which ? tW3 : sW3;
    const float *B3 = which ? tb3 : sb3;
    float v = 0.f;
    if (a < 3584) {                 // A1: [t][l][j]
      int t = a >> 9; int rem = a & 511; int l = rem >> 3; int j = rem & 7;
      int m = 16 * t + (l & 15);
      int d = 8 * (l >> 4) + j;
      if (m < 100) {
        if (d == 31) v = B1[m];     // bias via always-zero dim-31 slot
        else v = W1[d * 100 + m];
      }
    } else if (a < 17920) {         // A2: [t][c][l][j]
      int b = a - 3584; int tc = b >> 9; int t = tc >> 2; int c = tc & 3;
      int rem = b & 511; int l = rem >> 3; int j = rem & 7;
      int m = 16 * t + (l & 15);
      int k = 32 * c + (j >> 2) * 16 + 4 * (l >> 4) + (j & 3);
      if (m < 100) {
        if (k < 100) v = W2[k * 100 + m];
        else if (k == 100) v = B2[m];
      }
    } else {                        // A3: [c][l][j], REPLICATED across rows m
      int b = a - 17920; int c = b >> 9; int rem = b & 511;
      int l = rem >> 3; int j = rem & 7;
      int k = 32 * c + (j >> 2) * 16 + 4 * (l >> 4) + (j & 3);
      (void)l;
      if (k < 100) v = W3[k];
      else if (k == 100) v = B3[0];
    }
    wpk[gid] = (unsigned short)bf16u(v);
  } else if (gid < WPK_U16 + 512) { // AND-masks: [i][G][p]
    int idx = gid - WPK_U16;
    int i = idx >> 4;
    int G = (idx >> 2) & 3;
    int p = idx & 3;
    int d0 = 8 * G + 2 * p;
    unsigned int u = 0;
    if (C[d0 * 32 + i] != 0.f) u |= 0x0000FFFFu;
    if (C[(d0 + 1) * 32 + i] != 0.f) u |= 0xFFFF0000u;
    mpk[idx] = u;
  }
}

// ---------------- main kernel: one wave, 16 batch rows per tile -------------
__global__ __launch_bounds__(64, 1) void flow_main(
    const float *__restrict__ e, const unsigned short *__restrict__ wpk,
    const unsigned int *__restrict__ mpk, float *__restrict__ out) {
  const int lane = threadIdx.x;
  const int G = lane >> 4;
  const int bl = lane & 15;
  const bool g1 = (G == 1);
  const bool g3 = (G == 3);

  __shared__ __align__(16) unsigned int msk[512];
  {
    const uint4v *s = (const uint4v *)mpk;
    uint4v *d = (uint4v *)msk;
    d[lane] = s[lane];
    d[lane + 64] = s[lane + 64];
  }

  const short8 *w = (const short8 *)wpk;
  short8 a1s[7], a2s[7][4], a3s[4];
  short8 a1t[7], a2t[7][4], a3t[4];
#pragma unroll
  for (int t = 0; t < 7; ++t) a1s[t] = w[t * 64 + lane];
#pragma unroll
  for (int t = 0; t < 7; ++t)
#pragma unroll
    for (int c = 0; c < 4; ++c) a2s[t][c] = w[448 + (t * 4 + c) * 64 + lane];
#pragma unroll
  for (int c = 0; c < 4; ++c) a3s[c] = w[2240 + c * 64 + lane];
#pragma unroll
  for (int t = 0; t < 7; ++t) a1t[t] = w[2496 + t * 64 + lane];
#pragma unroll
  for (int t = 0; t < 7; ++t)
#pragma unroll
    for (int c = 0; c < 4; ++c)
      a2t[t][c] = w[2496 + 448 + (t * 4 + c) * 64 + lane];
#pragma unroll
  for (int c = 0; c < 4; ++c) a3t[c] = w[2496 + 2240 + c * 64 + lane];

  // ---- R11: pin A2 (2x28 frags = 224 regs) and A3 (2x4 frags = 32 regs)
  // to AGPRs — exactly 256, the AGPR file. A1 + working set stay VGPR.
#pragma unroll
  for (int t = 0; t < 7; ++t)
#pragma unroll
    for (int c = 0; c < 4; ++c) {
      asm volatile("" : "+a"(a2s[t][c]));
      asm volatile("" : "+a"(a2t[t][c]));
    }
#pragma unroll
  for (int c = 0; c < 4; ++c) {
    asm volatile("" : "+a"(a3s[c]));
    asm volatile("" : "+a"(a3t[c]));
  }

#pragma unroll 1
  for (int rep = 0; rep < REPS; ++rep) {
    const long base = ((long)blockIdx.x * REPS + rep) * 16;
    const float *ep = e + (base + bl) * 32 + G * 8;
    f32x4 e0 = *(const f32x4 *)ep;
    f32x4 e1 = *(const f32x4 *)(ep + 4);
    unsigned int z0 = 0, z1 = 0, z2 = 0, z3 = 0;  // z packed bf16, slots 0..7
    float ld = 0.f;
    uint4v m = *(const uint4v *)&msk[G * 4];  // mask for step 0

#pragma unroll 1
    for (int i8 = 0; i8 < 4; ++i8) {
      const bool tg = (G == i8);  // hoisted target-group predicate
#pragma unroll
      for (int u = 0; u < 8; ++u) {
        const int i = i8 * 8 + u;
        uint4v mn = *(const uint4v *)&msk[((i + 1) & 31) * 16 + G * 4];
        unsigned int x0 = z0 & m.x, x1 = z1 & m.y, x2 = z2 & m.z, x3 = z3 & m.w;
        if (g3) x3 = (x3 & 0x0000FFFFu) | 0x3F800000u;  // slot31 := 1.0
        uint4v xu; xu.x = x0; xu.y = x1; xu.z = x2; xu.w = x3;
        short8 x = __builtin_bit_cast(short8, xu);

        float sp, tp;
        mlp2_eval(a1s, a2s, a3s, a1t, a2t, a3t, x, g1, sp, tp);
        float sv = __fdividef(1.f, 1.f + __expf(-sp));
        float tv = __fdividef(1.f, 1.f + __expf(-tp));
        ld += sv;

        float es = (u < 4) ? e0[u] : e1[u - 4];   // static under unroll
        float zn = __expf(sv) * es + tv;
        unsigned int r = cvtpk(zn, zn);           // lo & hi both bf16(zn)
        const int p = (u >> 1) & 3;
        const bool hi = (u & 1) != 0;
        unsigned int mrg;
        if (p == 0) {
          mrg = hi ? ((z0 & 0x0000FFFFu) | (r & 0xFFFF0000u))
                   : ((z0 & 0xFFFF0000u) | (r & 0x0000FFFFu));
          z0 = tg ? mrg : z0;
        } else if (p == 1) {
          mrg = hi ? ((z1 & 0x0000FFFFu) | (r & 0xFFFF0000u))
                   : ((z1 & 0xFFFF0000u) | (r & 0x0000FFFFu));
          z1 = tg ? mrg : z1;
        } else if (p == 2) {
          mrg = hi ? ((z2 & 0x0000FFFFu) | (r & 0xFFFF0000u))
                   : ((z2 & 0xFFFF0000u) | (r & 0x0000FFFFu));
          z2 = tg ? mrg : z2;
        } else {
          mrg = hi ? ((z3 & 0x0000FFFFu) | (r & 0xFFFF0000u))
                   : ((z3 & 0xFFFF0000u) | (r & 0x0000FFFFu));
          z3 = tg ? mrg : z3;
        }
        m = mn;
      }
    }

    float *zo = out + (base + bl) * 32 + G * 8;
    f32x4 o0, o1;
    o0[0] = __uint_as_float(z0 << 16);
    o0[1] = __uint_as_float(z0 & 0xFFFF0000u);
    o0[2] = __uint_as_float(z1 << 16);
    o0[3] = __uint_as_float(z1 & 0xFFFF0000u);
    o1[0] = __uint_as_float(z2 << 16);
    o1[1] = __uint_as_float(z2 & 0xFFFF0000u);
    o1[2] = __uint_as_float(z3 << 16);
    o1[3] = __uint_as_float(z3 & 0xFFFF0000u);
    *(f32x4 *)zo = o0;
    *(f32x4 *)(zo + 4) = o1;
    if (lane < 16) out[(long)131072 * 32 + base + bl] = ld;
  }
}

extern "C" void kernel_launch(void *const *d_in, const int *in_sizes, int n_in,
                              void *d_out, int out_size, void *d_ws, size_t ws_size,
                              hipStream_t stream) {
  const float *e  = (const float *)d_in[0];
  const float *C  = (const float *)d_in[1];
  const float *sW1 = (const float *)d_in[2];
  const float *sb1 = (const float *)d_in[3];
  const float *sW2 = (const float *)d_in[4];
  const float *sb2 = (const float *)d_in[5];
  const float *sW3 = (const float *)d_in[6];
  const float *sb3 = (const float *)d_in[7];
  const float *tW1 = (const float *)d_in[8];
  const float *tb1 = (const float *)d_in[9];
  const float *tW2 = (const float *)d_in[10];
  const float *tb2 = (const float *)d_in[11];
  const float *tW3 = (const float *)d_in[12];
  const float *tb3 = (const float *)d_in[13];

  unsigned short *wpk = (unsigned short *)d_ws;
  unsigned int *mpk = (unsigned int *)((char *)d_ws + MPK_OFF_BYTES);
  float *out = (float *)d_out;

  prepack_kernel<<<dim3(159), dim3(256), 0, stream>>>(
      C, sW1, sb1, sW2, sb2, sW3, sb3, tW1, tb1, tW2, tb2, tW3, tb3, wpk, mpk);
  flow_main<<<dim3(NBLK), dim3(64), 0, stream>>>(e, wpk, mpk, out);
}